// Round 1
// baseline (185.352 us; speedup 1.0000x reference)
//
#include <hip/hip_runtime.h>

// Deformable Conv2D: x(8,64,96,96) f32, offset(8,18,96,96) f32, W(64,64,3,3) f32
// -> out(8,64,96,96) f32.
// Strategy: pad+transpose x -> xt[8][98][98][64] (NHWC, zero border baked in),
// transpose W -> Wt[n][c][o]; then fused gather+implicit-GEMM kernel:
// 128 pixels/block, K chunked over the 9 kernel taps.

#define NB   8
#define NC   64
#define NO   64
#define NH   96
#define NW   96
#define HP   98          // padded spatial
#define NPT  9           // kernel points
#define PIXB 128         // pixels per block
#define PSTR 132         // LDS pixel stride for v chunk (16B-aligned, bank-friendly)

// ---------- shared parameter math (replicates reference exactly) ----------
struct DCParams { int u0, u1, v0, v1; float glt, grb, glb, grt; };

__device__ inline DCParams dc_params(const float* __restrict__ off, int b, int i, int j, int n) {
    const int a = n / 3, b2 = n % 3;
    const float offx = off[((size_t)(b * 18 + n) * NH + i) * NW + j];
    const float offy = off[((size_t)(b * 18 + 9 + n) * NH + i) * NW + j];
    float px = (float)(i + a) + offx;          // (i+1) + (a-1)
    float py = (float)(j + b2) + offy;         // (j+1) + (b2-1)
    const float fx = floorf(px), fy = floorf(py);
    const float x0 = fminf(fmaxf(fx, 0.f), 97.f);
    const float x1 = fminf(fmaxf(fx + 1.f, 0.f), 97.f);
    const float y0 = fminf(fmaxf(fy, 0.f), 97.f);
    const float y1 = fminf(fmaxf(fy + 1.f, 0.f), 97.f);
    // mask/replace: px -> clip(fx,0,97) == x0 when out of [1,96]; else px (already in range)
    px = (px < 1.f || px > 96.f) ? x0 : px;
    py = (py < 1.f || py > 96.f) ? y0 : py;
    const float wx0 = 1.f + x0 - px;
    const float wx1 = 1.f - x1 + px;
    const float wy0 = 1.f + y0 - py;
    const float wy1 = 1.f - y1 + py;
    DCParams p;
    p.u0 = (int)x0; p.u1 = (int)x1; p.v0 = (int)y0; p.v1 = (int)y1;
    p.glt = wx0 * wy0; p.grb = wx1 * wy1; p.glb = wx0 * wy1; p.grt = wx1 * wy0;
    return p;
}

// ---------- prep kernels ----------
__global__ __launch_bounds__(256) void zero_xt(float* __restrict__ xt, int n4) {
    int i = blockIdx.x * 256 + threadIdx.x;
    if (i < n4) {
        float4 z; z.x = z.y = z.z = z.w = 0.f;
        ((float4*)xt)[i] = z;
    }
}

__global__ __launch_bounds__(256) void make_wt(const float* __restrict__ W, float* __restrict__ Wt) {
    int t = blockIdx.x * 256 + threadIdx.x;   // t = (n*64 + c)*64 + o, 36864 total
    if (t < NPT * NC * NO) {
        int o = t & 63, c = (t >> 6) & 63, n = t >> 12;
        Wt[t] = W[(size_t)o * 576 + c * 9 + n];
    }
}

// x (b,c,96,96) -> xt (b, u=i+1, v=j+1, c) ; interior only (borders zeroed above)
__global__ __launch_bounds__(256) void fill_xt(const float* __restrict__ x, float* __restrict__ xt) {
    __shared__ float tile[64][17];
    const int blk = blockIdx.x;              // 8*96*6 = 4608
    const int jt = blk % 6;
    const int i  = (blk / 6) % 96;
    const int b  = blk / 576;
    const int j0 = jt * 16;
    const int t = threadIdx.x;
    {
        const int jj = t & 15, cq = t >> 4;  // cq 0..15
        #pragma unroll
        for (int r = 0; r < 4; ++r) {
            const int c = cq * 4 + r;
            tile[c][jj] = x[(((size_t)b * NC + c) * NH + i) * NW + j0 + jj];
        }
    }
    __syncthreads();
    {
        const int c = t & 63, jq = t >> 6;   // jq 0..3
        #pragma unroll
        for (int r = 0; r < 4; ++r) {
            const int jj = jq * 4 + r;
            xt[(((size_t)b * HP + (i + 1)) * HP + (j0 + jj + 1)) * NC + c] = tile[c][jj];
        }
    }
}

// ---------- params -> LDS for main kernel ----------
__device__ inline void store_params_main(const float* __restrict__ off, int b, int pb, int pix, int n,
                                         int* __restrict__ sIb, float* __restrict__ sGb) {
    const int pp = pb + pix;
    const int i = pp / 96, j = pp - (pp / 96) * 96;
    const DCParams p = dc_params(off, b, i, j, n);
    const int base = b * (HP * HP * NC);
    sIb[0 * PIXB + pix] = base + (p.u0 * HP + p.v0) * NC;
    sIb[1 * PIXB + pix] = base + (p.u1 * HP + p.v1) * NC;
    sIb[2 * PIXB + pix] = base + (p.u0 * HP + p.v1) * NC;
    sIb[3 * PIXB + pix] = base + (p.u1 * HP + p.v0) * NC;
    sGb[0 * PIXB + pix] = p.glt;
    sGb[1 * PIXB + pix] = p.grb;
    sGb[2 * PIXB + pix] = p.glb;
    sGb[3 * PIXB + pix] = p.grt;
}

// ---------- main fused kernel ----------
__global__ __launch_bounds__(256) void deform_main(const float* __restrict__ xt, const float* __restrict__ Wt,
                                                   const float* __restrict__ off, float* __restrict__ out) {
    __shared__ float sV[NC * PSTR];          // 8448 floats; reused as outT[64][128] in epilogue
    __shared__ int   sI[2][4 * PIXB];
    __shared__ float sG[2][4 * PIXB];

    const int t  = threadIdx.x;
    const int P0 = blockIdx.x * PIXB;
    const int b  = P0 / (NH * NW);
    const int pb = P0 - b * (NH * NW);

    if (t < PIXB) store_params_main(off, b, pb, t, 0, sI[0], sG[0]);
    __syncthreads();

    const int od = t & 7;                    // o-octet: o = od*8 + jj
    const int pg = t >> 3;                   // pixel quad 0..31: pix = pg*4 + m
    float acc[4][8];
    #pragma unroll
    for (int m = 0; m < 4; ++m)
        #pragma unroll
        for (int jj = 0; jj < 8; ++jj) acc[m][jj] = 0.f;

    for (int n = 0; n < NPT; ++n) {
        const int cb = n & 1;
        // ---- gather phase: 512 tasks = 128 pixels x 4 channel-chunks of 16 ----
        #pragma unroll
        for (int r = 0; r < 2; ++r) {
            const int q   = t + (r << 8);
            const int pix = q >> 2, cc = q & 3;
            const int   i0 = sI[cb][0 * PIXB + pix], i1 = sI[cb][1 * PIXB + pix];
            const int   i2 = sI[cb][2 * PIXB + pix], i3 = sI[cb][3 * PIXB + pix];
            const float g0 = sG[cb][0 * PIXB + pix], g1 = sG[cb][1 * PIXB + pix];
            const float g2 = sG[cb][2 * PIXB + pix], g3 = sG[cb][3 * PIXB + pix];
            const int c0 = cc << 4;
            #pragma unroll
            for (int cq = 0; cq < 4; ++cq) {
                const int c = c0 + (cq << 2);
                const float4 t0 = *(const float4*)(xt + i0 + c);
                const float4 t1 = *(const float4*)(xt + i1 + c);
                const float4 t2 = *(const float4*)(xt + i2 + c);
                const float4 t3 = *(const float4*)(xt + i3 + c);
                sV[(c + 0) * PSTR + pix] = g0 * t0.x + g1 * t1.x + g2 * t2.x + g3 * t3.x;
                sV[(c + 1) * PSTR + pix] = g0 * t0.y + g1 * t1.y + g2 * t2.y + g3 * t3.y;
                sV[(c + 2) * PSTR + pix] = g0 * t0.z + g1 * t1.z + g2 * t2.z + g3 * t3.z;
                sV[(c + 3) * PSTR + pix] = g0 * t0.w + g1 * t1.w + g2 * t2.w + g3 * t3.w;
            }
        }
        __syncthreads();
        // overlap next chunk's params with GEMM
        if (n < NPT - 1 && t < PIXB) store_params_main(off, b, pb, t, n + 1, sI[cb ^ 1], sG[cb ^ 1]);
        // ---- GEMM phase: acc[m][jj] += v[c][pix(pg,m)] * Wt[n][c][od*8+jj] ----
        const float* wtn = Wt + (n << 12) + (od << 3);
        #pragma unroll 4
        for (int c = 0; c < 64; ++c) {
            const float4 v4 = *(const float4*)(&sV[c * PSTR + (pg << 2)]);
            const float4 wa = *(const float4*)(wtn + (c << 6));
            const float4 wb = *(const float4*)(wtn + (c << 6) + 4);
            const float vv[4] = {v4.x, v4.y, v4.z, v4.w};
            const float ww[8] = {wa.x, wa.y, wa.z, wa.w, wb.x, wb.y, wb.z, wb.w};
            #pragma unroll
            for (int m = 0; m < 4; ++m)
                #pragma unroll
                for (int jj = 0; jj < 8; ++jj)
                    acc[m][jj] += vv[m] * ww[jj];
        }
        __syncthreads();
    }

    // ---- epilogue: stage outT[o][pix] in LDS then coalesced float4 stores ----
    #pragma unroll
    for (int jj = 0; jj < 8; ++jj) {
        float4 wv;
        wv.x = acc[0][jj]; wv.y = acc[1][jj]; wv.z = acc[2][jj]; wv.w = acc[3][jj];
        *(float4*)(&sV[((od << 3) + jj) * PIXB + (pg << 2)]) = wv;
    }
    __syncthreads();
    const size_t ob = (size_t)b * NO * (NH * NW) + pb;
    #pragma unroll
    for (int e = t; e < NO * (PIXB / 4); e += 256) {   // 2048 float4 stores
        const int o = e >> 5, p4 = e & 31;
        const float4 v = *(const float4*)(&sV[o * PIXB + (p4 << 2)]);
        *(float4*)(out + ob + (size_t)o * (NH * NW) + (p4 << 2)) = v;
    }
}

// ---------- naive fallback (no workspace needed) ----------
__global__ __launch_bounds__(256) void deform_naive(const float* __restrict__ x, const float* __restrict__ W,
                                                    const float* __restrict__ off, float* __restrict__ out) {
    __shared__ float sv[576];
    __shared__ DCParams sp[NPT];
    const int t = threadIdx.x;
    const int P = blockIdx.x;
    const int b = P / (NH * NW), pp = P - b * (NH * NW);
    const int i = pp / 96, j = pp - (pp / 96) * 96;
    if (t < NPT) sp[t] = dc_params(off, b, i, j, t);
    __syncthreads();
    for (int k = t; k < 576; k += 256) {
        const int c = k / 9, n = k - c * 9;
        const DCParams p = sp[n];
        const float* xb = x + ((size_t)(b * NC + c)) * (NH * NW);
        const float vlt = (p.u0 >= 1 && p.u0 <= 96 && p.v0 >= 1 && p.v0 <= 96) ? xb[(p.u0 - 1) * 96 + (p.v0 - 1)] : 0.f;
        const float vrb = (p.u1 >= 1 && p.u1 <= 96 && p.v1 >= 1 && p.v1 <= 96) ? xb[(p.u1 - 1) * 96 + (p.v1 - 1)] : 0.f;
        const float vlb = (p.u0 >= 1 && p.u0 <= 96 && p.v1 >= 1 && p.v1 <= 96) ? xb[(p.u0 - 1) * 96 + (p.v1 - 1)] : 0.f;
        const float vrt = (p.u1 >= 1 && p.u1 <= 96 && p.v0 >= 1 && p.v0 <= 96) ? xb[(p.u1 - 1) * 96 + (p.v0 - 1)] : 0.f;
        sv[k] = p.glt * vlt + p.grb * vrb + p.glb * vlb + p.grt * vrt;
    }
    __syncthreads();
    if (t < NO) {
        const float* wrow = W + (size_t)t * 576;
        float acc = 0.f;
        for (int k = 0; k < 576; ++k) acc += sv[k] * wrow[k];
        out[((size_t)(b * NO + t)) * (NH * NW) + pp] = acc;
    }
}

extern "C" void kernel_launch(void* const* d_in, const int* in_sizes, int n_in,
                              void* d_out, int out_size, void* d_ws, size_t ws_size,
                              hipStream_t stream) {
    const float* x   = (const float*)d_in[0];
    const float* off = (const float*)d_in[1];
    const float* W   = (const float*)d_in[2];
    float* out = (float*)d_out;

    const size_t XT_FLOATS = (size_t)NB * HP * HP * NC;   // 4,917,248
    const size_t WT_FLOATS = (size_t)NPT * NC * NO;       // 36,864
    const size_t need = (XT_FLOATS + WT_FLOATS) * sizeof(float);

    if (ws_size >= need) {
        float* xt = (float*)d_ws;
        float* Wt = xt + XT_FLOATS;
        zero_xt<<<dim3((unsigned)(XT_FLOATS / 4 / 256)), dim3(256), 0, stream>>>(xt, (int)(XT_FLOATS / 4));
        make_wt<<<dim3(144), dim3(256), 0, stream>>>(W, Wt);
        fill_xt<<<dim3(NB * 96 * 6), dim3(256), 0, stream>>>(x, xt);
        deform_main<<<dim3((NB * NH * NW) / PIXB), dim3(256), 0, stream>>>(xt, Wt, off, out);
    } else {
        deform_naive<<<dim3(NB * NH * NW), dim3(256), 0, stream>>>(x, W, off, out);
    }
}

// Round 3
// 79.535 us; speedup vs baseline: 2.3304x; 2.3304x over previous
//
#include <hip/hip_runtime.h>

// Deformable Conv2D, MFMA version (race-free 2-barrier schedule).
// x(8,64,96,96) f32, offset(8,18,96,96) f32, W(64,64,3,3) f32 -> out(8,64,96,96) f32.
// Prep: xt = bf16 NHWC padded [8][98][98][64] (zero border baked in);
//       Bt = bf16 MFMA B-fragments [9 taps][2 kk][4 ntile][64 lane][8].
// Main: 1152 blocks x 256 thr; block = 64 pixels x 64 outputs, K = 9 taps x 64 ch.
//       Per tap: barrier -> bilinear->LDS write -> barrier -> MFMA (single buffer).
//       One batch image per XCD (1152 = 8*144) so gathers are L2-resident.

typedef __bf16 bf16_t;
typedef __bf16 bf16x8 __attribute__((ext_vector_type(8)));
typedef float  f32x4  __attribute__((ext_vector_type(4)));

#define NB 8
#define NC 64
#define NO 64
#define NH 96
#define NW 96
#define HP 98
#define NPT 9
#define PIX 64           // pixels per block
#define ASTR 72          // sA row stride in bf16 (144B -> bank-shifted rows)

// ---------- parameter math (identical to round-0 verified version) ----------
struct DCParams { int u0, u1, v0, v1; float glt, grb, glb, grt; };

__device__ __forceinline__ DCParams dc_params(const float* __restrict__ off, int b, int i, int j, int n) {
    const int a = n / 3, b2 = n % 3;
    const float offx = off[((size_t)(b * 18 + n) * NH + i) * NW + j];
    const float offy = off[((size_t)(b * 18 + 9 + n) * NH + i) * NW + j];
    float px = (float)(i + a) + offx;
    float py = (float)(j + b2) + offy;
    const float fx = floorf(px), fy = floorf(py);
    const float x0 = fminf(fmaxf(fx, 0.f), 97.f);
    const float x1 = fminf(fmaxf(fx + 1.f, 0.f), 97.f);
    const float y0 = fminf(fmaxf(fy, 0.f), 97.f);
    const float y1 = fminf(fmaxf(fy + 1.f, 0.f), 97.f);
    px = (px < 1.f || px > 96.f) ? x0 : px;
    py = (py < 1.f || py > 96.f) ? y0 : py;
    const float wx0 = 1.f + x0 - px;
    const float wx1 = 1.f - x1 + px;
    const float wy0 = 1.f + y0 - py;
    const float wy1 = 1.f - y1 + py;
    DCParams p;
    p.u0 = (int)x0; p.u1 = (int)x1; p.v0 = (int)y0; p.v1 = (int)y1;
    p.glt = wx0 * wy0; p.grb = wx1 * wy1; p.glb = wx0 * wy1; p.grt = wx1 * wy0;
    return p;
}

// ---------- prep kernels ----------
__global__ __launch_bounds__(256) void zero_xt16(uint4* __restrict__ xt, int n16) {
    int i = blockIdx.x * 256 + threadIdx.x;
    if (i < n16) { uint4 z = {0, 0, 0, 0}; xt[i] = z; }
}

// x (b,c,96,96) f32 -> xt (b, i+1, j+1, c) bf16 (interior; border pre-zeroed)
__global__ __launch_bounds__(256) void fill_xt16(const float* __restrict__ x, bf16_t* __restrict__ xt) {
    __shared__ float tile[64][17];
    const int blk = blockIdx.x;              // 8*96*6 = 4608
    const int jt = blk % 6;
    const int i  = (blk / 6) % 96;
    const int b  = blk / 576;
    const int j0 = jt * 16;
    const int t = threadIdx.x;
    {
        const int jj = t & 15, cq = t >> 4;
        #pragma unroll
        for (int r = 0; r < 4; ++r) {
            const int c = cq * 4 + r;
            tile[c][jj] = x[(((size_t)b * NC + c) * NH + i) * NW + j0 + jj];
        }
    }
    __syncthreads();
    {
        const int c = t & 63, jq = t >> 6;
        #pragma unroll
        for (int r = 0; r < 4; ++r) {
            const int jj = jq * 4 + r;
            xt[(((size_t)b * HP + (i + 1)) * HP + (j0 + jj + 1)) * NC + c] = (bf16_t)tile[c][jj];
        }
    }
}

// W[o][c][3][3] f32 -> Bt bf16 fragments: frag = (n*2+kk)*4+nt, elem = lane*8+j
// value = W[o = nt*16 + (lane&15)][c = kk*32 + 8*(lane>>4) + j][tap n]
__global__ __launch_bounds__(256) void make_bt(const float* __restrict__ W, bf16_t* __restrict__ Bt) {
    int t = blockIdx.x * 256 + threadIdx.x;   // 36864 total
    if (t < NPT * NC * NO) {
        const int j = t & 7, l = (t >> 3) & 63, frag = t >> 9;
        const int nt = frag & 3, kk = (frag >> 2) & 1, n = frag >> 3;
        const int o = nt * 16 + (l & 15);
        const int c = kk * 32 + 8 * (l >> 4) + j;
        Bt[t] = (bf16_t)W[(size_t)o * 576 + c * 9 + n];
    }
}

// ---------- main kernel ----------
struct Stage {
    bf16x8 c00a, c00b, c11a, c11b, c01a, c01b, c10a, c10b;
    float g0, g1, g2, g3;
};

__device__ __forceinline__ Stage stage_load(const bf16_t* __restrict__ xt, const float* __restrict__ off,
                                            int b, int i, int j, int n, int cg) {
    const DCParams p = dc_params(off, b, i, j, n);
    const bf16_t* base = xt + (size_t)b * (HP * HP * NC) + cg * 16;
    const bf16_t* pA = base + (p.u0 * HP + p.v0) * NC;   // lt
    const bf16_t* pB = base + (p.u1 * HP + p.v1) * NC;   // rb
    const bf16_t* pC = base + (p.u0 * HP + p.v1) * NC;   // lb
    const bf16_t* pD = base + (p.u1 * HP + p.v0) * NC;   // rt
    Stage s;
    s.c00a = *(const bf16x8*)(pA); s.c00b = *(const bf16x8*)(pA + 8);
    s.c11a = *(const bf16x8*)(pB); s.c11b = *(const bf16x8*)(pB + 8);
    s.c01a = *(const bf16x8*)(pC); s.c01b = *(const bf16x8*)(pC + 8);
    s.c10a = *(const bf16x8*)(pD); s.c10b = *(const bf16x8*)(pD + 8);
    s.g0 = p.glt; s.g1 = p.grb; s.g2 = p.glb; s.g3 = p.grt;
    return s;
}

__device__ __forceinline__ void stage_finish(const Stage& s, bf16_t* dst) {
    bf16x8 r0, r1;
    #pragma unroll
    for (int e = 0; e < 8; ++e) {
        const float v = s.g0 * (float)s.c00a[e] + s.g1 * (float)s.c11a[e]
                      + s.g2 * (float)s.c01a[e] + s.g3 * (float)s.c10a[e];
        r0[e] = (bf16_t)v;
    }
    #pragma unroll
    for (int e = 0; e < 8; ++e) {
        const float v = s.g0 * (float)s.c00b[e] + s.g1 * (float)s.c11b[e]
                      + s.g2 * (float)s.c01b[e] + s.g3 * (float)s.c10b[e];
        r1[e] = (bf16_t)v;
    }
    *(bf16x8*)(dst)     = r0;
    *(bf16x8*)(dst + 8) = r1;
}

__device__ __forceinline__ void mfma_tap(const bf16_t* sAbuf, const bf16_t* __restrict__ Bt,
                                         int n, int w, int l, f32x4 acc[4]) {
    const int mrow = l & 15, khi = l >> 4;
    #pragma unroll
    for (int kk = 0; kk < 2; ++kk) {
        const bf16x8 bf = *(const bf16x8*)(Bt + (size_t)(((n * 2 + kk) * 4 + w)) * 512 + l * 8);
        #pragma unroll
        for (int mt = 0; mt < 4; ++mt) {
            const bf16x8 af = *(const bf16x8*)(sAbuf + (mt * 16 + mrow) * ASTR + kk * 32 + khi * 8);
            acc[mt] = __builtin_amdgcn_mfma_f32_16x16x32_bf16(af, bf, acc[mt], 0, 0, 0);
        }
    }
}

__global__ __launch_bounds__(256) void deform_mfma(const bf16_t* __restrict__ xt, const bf16_t* __restrict__ Bt,
                                                   const float* __restrict__ off, float* __restrict__ out) {
    // union region: bf16 sA[64][72] (9216 B) during main loop; f32 sO[64][68] (17408 B) in epilogue
    __shared__ __align__(16) unsigned char smem[NO * 68 * 4];
    bf16_t* sA = (bf16_t*)smem;
    float*  sO = (float*)smem;

    const int t = threadIdx.x;
    const int l = t & 63;        // lane
    const int w = t >> 6;        // wave id = output-channel tile = gather channel-group
    const int bid = blockIdx.x;
    const int b  = bid & 7;      // one batch image per XCD (blocks round-robin across 8 XCDs)
    const int pb = (bid >> 3) * PIX;
    const int pp = pb + l;
    const int i = pp / 96, j = pp - (pp / 96) * 96;

    f32x4 acc[4] = {};

    Stage s = stage_load(xt, off, b, i, j, 0, w);   // prologue: issue tap-0 loads

    for (int n = 0; n < NPT; ++n) {
        __syncthreads();                             // all reads of sA (tap n-1) retired
        stage_finish(s, sA + l * ASTR + w * 16);     // bilinear combine -> LDS
        if (n + 1 < NPT) s = stage_load(xt, off, b, i, j, n + 1, w);  // issue next loads
        __syncthreads();                             // sA writes visible
        mfma_tap(sA, Bt, n, w, l, acc);              // LDS reads + MFMA (hides loads)
    }

    __syncthreads();                                 // final mfma LDS reads retired before reuse

    // epilogue: acc -> LDS [o][pix] f32, then coalesced float4 stores
    const int orow = w * 16 + (l & 15);
    #pragma unroll
    for (int mt = 0; mt < 4; ++mt)
        #pragma unroll
        for (int r = 0; r < 4; ++r)
            sO[orow * 68 + mt * 16 + (l >> 4) * 4 + r] = acc[mt][r];
    __syncthreads();

    const int o = t >> 2, q = t & 3;
    float4* dst = (float4*)(out + ((size_t)(b * NO + o)) * (NH * NW) + pb + q * 16);
    const float* src = sO + o * 68 + q * 16;
    #pragma unroll
    for (int k2 = 0; k2 < 4; ++k2) dst[k2] = ((const float4*)src)[k2];
}

// ---------- naive fallback (no workspace needed) ----------
__global__ __launch_bounds__(256) void deform_naive(const float* __restrict__ x, const float* __restrict__ W,
                                                    const float* __restrict__ off, float* __restrict__ out) {
    __shared__ float sv[576];
    __shared__ DCParams sp[NPT];
    const int t = threadIdx.x;
    const int P = blockIdx.x;
    const int b = P / (NH * NW), pp = P - b * (NH * NW);
    const int i = pp / 96, j = pp - (pp / 96) * 96;
    if (t < NPT) sp[t] = dc_params(off, b, i, j, t);
    __syncthreads();
    for (int k = t; k < 576; k += 256) {
        const int c = k / 9, n = k - c * 9;
        const DCParams p = sp[n];
        const float* xb = x + ((size_t)(b * NC + c)) * (NH * NW);
        const float vlt = (p.u0 >= 1 && p.u0 <= 96 && p.v0 >= 1 && p.v0 <= 96) ? xb[(p.u0 - 1) * 96 + (p.v0 - 1)] : 0.f;
        const float vrb = (p.u1 >= 1 && p.u1 <= 96 && p.v1 >= 1 && p.v1 <= 96) ? xb[(p.u1 - 1) * 96 + (p.v1 - 1)] : 0.f;
        const float vlb = (p.u0 >= 1 && p.u0 <= 96 && p.v1 >= 1 && p.v1 <= 96) ? xb[(p.u0 - 1) * 96 + (p.v1 - 1)] : 0.f;
        const float vrt = (p.u1 >= 1 && p.u1 <= 96 && p.v0 >= 1 && p.v0 <= 96) ? xb[(p.u1 - 1) * 96 + (p.v0 - 1)] : 0.f;
        sv[k] = p.glt * vlt + p.grb * vrb + p.glb * vlb + p.grt * vrt;
    }
    __syncthreads();
    if (t < NO) {
        const float* wrow = W + (size_t)t * 576;
        float acc = 0.f;
        for (int k = 0; k < 576; ++k) acc += sv[k] * wrow[k];
        out[((size_t)(b * NO + t)) * (NH * NW) + pp] = acc;
    }
}

extern "C" void kernel_launch(void* const* d_in, const int* in_sizes, int n_in,
                              void* d_out, int out_size, void* d_ws, size_t ws_size,
                              hipStream_t stream) {
    const float* x   = (const float*)d_in[0];
    const float* off = (const float*)d_in[1];
    const float* W   = (const float*)d_in[2];
    float* out = (float*)d_out;

    const size_t XT_ELEMS = (size_t)NB * HP * HP * NC;     // 4,917,248 bf16
    const size_t XT_BYTES = XT_ELEMS * 2;                  // 9,834,496 (mult of 16)
    const size_t BT_ELEMS = (size_t)NPT * NC * NO;         // 36,864 bf16
    const size_t need = XT_BYTES + BT_ELEMS * 2;

    if (ws_size >= need) {
        bf16_t* xt = (bf16_t*)d_ws;
        bf16_t* Bt = (bf16_t*)((char*)d_ws + XT_BYTES);
        const int n16 = (int)(XT_BYTES / 16);              // 614,656
        zero_xt16<<<dim3((n16 + 255) / 256), dim3(256), 0, stream>>>((uint4*)xt, n16);
        make_bt<<<dim3(144), dim3(256), 0, stream>>>(W, Bt);
        fill_xt16<<<dim3(NB * 96 * 6), dim3(256), 0, stream>>>(x, xt);
        deform_mfma<<<dim3((NB * NH * NW) / PIX), dim3(256), 0, stream>>>(xt, Bt, off, out);
    } else {
        deform_naive<<<dim3(NB * NH * NW), dim3(256), 0, stream>>>(x, W, off, out);
    }
}